// Round 1
// baseline (1610.651 us; speedup 1.0000x reference)
//
#include <hip/hip_runtime.h>
#include <hip/hip_bf16.h>
#include <math.h>

#define B_ 128
#define S_ 2048
#define D_IN_ 512
#define D_MODEL_ 2048
#define M_ 25
#define NSY_ 64
#define H_ 8
#define T_ 10
#define REP_ 2080
#define DH_ 64
#define PRED_N (B_ * 4096)

typedef unsigned short ushort_t;
typedef __bf16 bf16x8 __attribute__((ext_vector_type(8)));
typedef float f32x4 __attribute__((ext_vector_type(4)));
typedef unsigned short us8 __attribute__((ext_vector_type(8)));

__device__ __forceinline__ ushort_t f2bf(float f) {
    __hip_bfloat16 h = __float2bfloat16(f);
    return *(ushort_t*)&h;
}

// ---------------------------------------------------------------------------
// MFMA bf16 GEMM, f32 A (cast during staging): C[M,N] (+)= A @ Bt^T
// grid = (N/128, M/64, Z). Z==1: direct store + bias. Z>1: atomicAdd.
// ---------------------------------------------------------------------------
__global__ __launch_bounds__(256) void gemm_bf16(
    const float* __restrict__ A, int lda,
    const ushort_t* __restrict__ Bt, int ldb,
    const float* __restrict__ bias,
    float* __restrict__ C, int ldc,
    int M, int N, int K, int kchunk)
{
    const int nb = blockIdx.x, mb = blockIdx.y, zb = blockIdx.z;
    const int k0 = zb * kchunk;
    const int k1 = min(K, k0 + kchunk);
    __shared__ ushort_t As[64][40];
    __shared__ ushort_t Bs[128][40];

    const int tid  = threadIdx.x;
    const int wave = tid >> 6;
    const int lane = tid & 63;
    const int quad = lane >> 4;
    const int mrow = lane & 15;

    f32x4 acc[4][2];
    #pragma unroll
    for (int s = 0; s < 4; s++)
        #pragma unroll
        for (int u = 0; u < 2; u++)
            acc[s][u] = (f32x4){0.f, 0.f, 0.f, 0.f};

    const int arow = tid >> 2, akc = (tid & 3) * 8;
    const int brow = tid >> 1, bkc = (tid & 1) * 16;

    for (int kk0 = k0; kk0 < k1; kk0 += 32) {
        {
            const float* ap = A + (size_t)(mb * 64 + arow) * lda + kk0 + akc;
            float4 v0 = *(const float4*)ap;
            float4 v1 = *(const float4*)(ap + 4);
            us8 w = { f2bf(v0.x), f2bf(v0.y), f2bf(v0.z), f2bf(v0.w),
                      f2bf(v1.x), f2bf(v1.y), f2bf(v1.z), f2bf(v1.w) };
            *(us8*)&As[arow][akc] = w;
        }
        {
            const ushort_t* bp = Bt + (size_t)(nb * 128 + brow) * ldb + kk0 + bkc;
            *(us8*)&Bs[brow][bkc]     = *(const us8*)bp;
            *(us8*)&Bs[brow][bkc + 8] = *(const us8*)(bp + 8);
        }
        __syncthreads();

        bf16x8 af[4], bfr[2];
        #pragma unroll
        for (int s = 0; s < 4; s++)
            af[s] = *(const bf16x8*)&As[s * 16 + mrow][quad * 8];
        #pragma unroll
        for (int u = 0; u < 2; u++)
            bfr[u] = *(const bf16x8*)&Bs[wave * 32 + u * 16 + mrow][quad * 8];
        #pragma unroll
        for (int s = 0; s < 4; s++)
            #pragma unroll
            for (int u = 0; u < 2; u++)
                acc[s][u] = __builtin_amdgcn_mfma_f32_16x16x32_bf16(
                    af[s], bfr[u], acc[s][u], 0, 0, 0);
        __syncthreads();
    }

    if (gridDim.z == 1) {
        #pragma unroll
        for (int s = 0; s < 4; s++)
            #pragma unroll
            for (int u = 0; u < 2; u++) {
                const int col = nb * 128 + wave * 32 + u * 16 + mrow;
                #pragma unroll
                for (int reg = 0; reg < 4; reg++) {
                    const int row = mb * 64 + s * 16 + quad * 4 + reg;
                    C[(size_t)row * ldc + col] = acc[s][u][reg] + bias[col];
                }
            }
    } else {
        #pragma unroll
        for (int s = 0; s < 4; s++)
            #pragma unroll
            for (int u = 0; u < 2; u++) {
                const int col = nb * 128 + wave * 32 + u * 16 + mrow;
                #pragma unroll
                for (int reg = 0; reg < 4; reg++) {
                    const int row = mb * 64 + s * 16 + quad * 4 + reg;
                    atomicAdd(&C[(size_t)row * ldc + col], acc[s][u][reg]);
                }
            }
    }
}

// ---------------------------------------------------------------------------
// Same GEMM but A already bf16 (pure-copy staging). Used for q(0) prologue.
// ---------------------------------------------------------------------------
__global__ __launch_bounds__(256) void gemm_bb(
    const ushort_t* __restrict__ A, int lda,
    const ushort_t* __restrict__ Bt, int ldb,
    const float* __restrict__ bias,
    float* __restrict__ C, int ldc,
    int M, int N, int K, int kchunk)
{
    const int nb = blockIdx.x, mb = blockIdx.y, zb = blockIdx.z;
    const int k0 = zb * kchunk;
    const int k1 = min(K, k0 + kchunk);
    __shared__ ushort_t As[64][40];
    __shared__ ushort_t Bs[128][40];

    const int tid  = threadIdx.x;
    const int wave = tid >> 6;
    const int lane = tid & 63;
    const int quad = lane >> 4;
    const int mrow = lane & 15;

    f32x4 acc[4][2];
    #pragma unroll
    for (int s = 0; s < 4; s++)
        #pragma unroll
        for (int u = 0; u < 2; u++)
            acc[s][u] = (f32x4){0.f, 0.f, 0.f, 0.f};

    const int arow = tid >> 2, akc = (tid & 3) * 8;
    const int brow = tid >> 1, bkc = (tid & 1) * 16;

    for (int kk0 = k0; kk0 < k1; kk0 += 32) {
        {
            const ushort_t* ap = A + (size_t)(mb * 64 + arow) * lda + kk0 + akc;
            *(us8*)&As[arow][akc] = *(const us8*)ap;
        }
        {
            const ushort_t* bp = Bt + (size_t)(nb * 128 + brow) * ldb + kk0 + bkc;
            *(us8*)&Bs[brow][bkc]     = *(const us8*)bp;
            *(us8*)&Bs[brow][bkc + 8] = *(const us8*)(bp + 8);
        }
        __syncthreads();

        bf16x8 af[4], bfr[2];
        #pragma unroll
        for (int s = 0; s < 4; s++)
            af[s] = *(const bf16x8*)&As[s * 16 + mrow][quad * 8];
        #pragma unroll
        for (int u = 0; u < 2; u++)
            bfr[u] = *(const bf16x8*)&Bs[wave * 32 + u * 16 + mrow][quad * 8];
        #pragma unroll
        for (int s = 0; s < 4; s++)
            #pragma unroll
            for (int u = 0; u < 2; u++)
                acc[s][u] = __builtin_amdgcn_mfma_f32_16x16x32_bf16(
                    af[s], bfr[u], acc[s][u], 0, 0, 0);
        __syncthreads();
    }

    if (gridDim.z == 1) {
        #pragma unroll
        for (int s = 0; s < 4; s++)
            #pragma unroll
            for (int u = 0; u < 2; u++) {
                const int col = nb * 128 + wave * 32 + u * 16 + mrow;
                #pragma unroll
                for (int reg = 0; reg < 4; reg++) {
                    const int row = mb * 64 + s * 16 + quad * 4 + reg;
                    C[(size_t)row * ldc + col] = acc[s][u][reg] + bias[col];
                }
            }
    } else {
        #pragma unroll
        for (int s = 0; s < 4; s++)
            #pragma unroll
            for (int u = 0; u < 2; u++) {
                const int col = nb * 128 + wave * 32 + u * 16 + mrow;
                #pragma unroll
                for (int reg = 0; reg < 4; reg++) {
                    const int row = mb * 64 + s * 16 + quad * 4 + reg;
                    atomicAdd(&C[(size_t)row * ldc + col], acc[s][u][reg]);
                }
            }
    }
}

// ---------------------------------------------------------------------------
// Dual bf16-A GEMM (both K=REP_, M=128, atomic epilogue): one launch runs
// Wout-GEMM(t) [blocks < nblk1] and q-GEMM(t+1) [blocks >= nblk1].
// Both depend only on state_trace(t); merging removes a serial dispatch and
// fills the CUs (320 + 104 = 424 blocks).
// ---------------------------------------------------------------------------
__global__ __launch_bounds__(256) void gemm_bb_dual(
    const ushort_t* __restrict__ A1, int lda1,
    const ushort_t* __restrict__ Bt1, int ldb1,
    float* __restrict__ C1, int ldc1, int kc1, int nb1x, int nblk1,
    const ushort_t* __restrict__ A2, int lda2,
    const ushort_t* __restrict__ Bt2, int ldb2,
    float* __restrict__ C2, int ldc2, int kc2, int nb2x)
{
    int bid = blockIdx.x;
    const ushort_t* A; const ushort_t* Bt; float* C;
    int lda, ldb, ldc, nb, mb, zb, kchunk;
    if (bid < nblk1) {
        A = A1; Bt = Bt1; C = C1; lda = lda1; ldb = ldb1; ldc = ldc1; kchunk = kc1;
        nb = bid % nb1x; mb = (bid / nb1x) & 1; zb = bid / (nb1x * 2);
    } else {
        bid -= nblk1;
        A = A2; Bt = Bt2; C = C2; lda = lda2; ldb = ldb2; ldc = ldc2; kchunk = kc2;
        nb = bid % nb2x; mb = (bid / nb2x) & 1; zb = bid / (nb2x * 2);
    }
    const int k0 = zb * kchunk;
    const int k1 = min(REP_, k0 + kchunk);
    __shared__ ushort_t As[64][40];
    __shared__ ushort_t Bs[128][40];

    const int tid  = threadIdx.x;
    const int wave = tid >> 6;
    const int lane = tid & 63;
    const int quad = lane >> 4;
    const int mrow = lane & 15;

    f32x4 acc[4][2];
    #pragma unroll
    for (int s = 0; s < 4; s++)
        #pragma unroll
        for (int u = 0; u < 2; u++)
            acc[s][u] = (f32x4){0.f, 0.f, 0.f, 0.f};

    const int arow = tid >> 2, akc = (tid & 3) * 8;
    const int brow = tid >> 1, bkc = (tid & 1) * 16;

    for (int kk0 = k0; kk0 < k1; kk0 += 32) {
        {
            const ushort_t* ap = A + (size_t)(mb * 64 + arow) * lda + kk0 + akc;
            *(us8*)&As[arow][akc] = *(const us8*)ap;
        }
        {
            const ushort_t* bp = Bt + (size_t)(nb * 128 + brow) * ldb + kk0 + bkc;
            *(us8*)&Bs[brow][bkc]     = *(const us8*)bp;
            *(us8*)&Bs[brow][bkc + 8] = *(const us8*)(bp + 8);
        }
        __syncthreads();

        bf16x8 af[4], bfr[2];
        #pragma unroll
        for (int s = 0; s < 4; s++)
            af[s] = *(const bf16x8*)&As[s * 16 + mrow][quad * 8];
        #pragma unroll
        for (int u = 0; u < 2; u++)
            bfr[u] = *(const bf16x8*)&Bs[wave * 32 + u * 16 + mrow][quad * 8];
        #pragma unroll
        for (int s = 0; s < 4; s++)
            #pragma unroll
            for (int u = 0; u < 2; u++)
                acc[s][u] = __builtin_amdgcn_mfma_f32_16x16x32_bf16(
                    af[s], bfr[u], acc[s][u], 0, 0, 0);
        __syncthreads();
    }

    #pragma unroll
    for (int s = 0; s < 4; s++)
        #pragma unroll
        for (int u = 0; u < 2; u++) {
            const int col = nb * 128 + wave * 32 + u * 16 + mrow;
            #pragma unroll
            for (int reg = 0; reg < 4; reg++) {
                const int row = mb * 64 + s * 16 + quad * 4 + reg;
                atomicAdd(&C[(size_t)row * ldc + col], acc[s][u][reg]);
            }
        }
}

// ---------------------------------------------------------------------------
// QK scores, dense both-token: sc[(c*8+h)*128+b][s] = 0.125 * q_bh . K_chs
// grid = (S/128, B/64, 16)
// ---------------------------------------------------------------------------
__global__ __launch_bounds__(256) void gemm_qk(
    const float* __restrict__ q,
    const ushort_t* __restrict__ Kb,
    float* __restrict__ sc)
{
    const int nb = blockIdx.x, mb = blockIdx.y, z = blockIdx.z;
    const int c = z >> 3, h = z & 7;
    __shared__ ushort_t As[64][40];
    __shared__ ushort_t Bs[128][40];

    const int tid  = threadIdx.x;
    const int wave = tid >> 6;
    const int lane = tid & 63;
    const int quad = lane >> 4;
    const int mrow = lane & 15;

    f32x4 acc[4][2];
    #pragma unroll
    for (int s = 0; s < 4; s++)
        #pragma unroll
        for (int u = 0; u < 2; u++)
            acc[s][u] = (f32x4){0.f, 0.f, 0.f, 0.f};

    const int arow = tid >> 2, akc = (tid & 3) * 8;
    const int brow = tid >> 1, bkc = (tid & 1) * 16;
    const float* Abase = q + (size_t)h * 64;
    const ushort_t* Bbase = Kb + (size_t)c * S_ * 512 + h * 64;

    #pragma unroll
    for (int kk0 = 0; kk0 < 64; kk0 += 32) {
        {
            const float* ap = Abase + (size_t)(mb * 64 + arow) * 512 + kk0 + akc;
            float4 v0 = *(const float4*)ap;
            float4 v1 = *(const float4*)(ap + 4);
            us8 w = { f2bf(v0.x), f2bf(v0.y), f2bf(v0.z), f2bf(v0.w),
                      f2bf(v1.x), f2bf(v1.y), f2bf(v1.z), f2bf(v1.w) };
            *(us8*)&As[arow][akc] = w;
        }
        {
            const ushort_t* bp = Bbase + (size_t)(nb * 128 + brow) * 512 + kk0 + bkc;
            *(us8*)&Bs[brow][bkc]     = *(const us8*)bp;
            *(us8*)&Bs[brow][bkc + 8] = *(const us8*)(bp + 8);
        }
        __syncthreads();

        bf16x8 af[4], bfr[2];
        #pragma unroll
        for (int s = 0; s < 4; s++)
            af[s] = *(const bf16x8*)&As[s * 16 + mrow][quad * 8];
        #pragma unroll
        for (int u = 0; u < 2; u++)
            bfr[u] = *(const bf16x8*)&Bs[wave * 32 + u * 16 + mrow][quad * 8];
        #pragma unroll
        for (int s = 0; s < 4; s++)
            #pragma unroll
            for (int u = 0; u < 2; u++)
                acc[s][u] = __builtin_amdgcn_mfma_f32_16x16x32_bf16(
                    af[s], bfr[u], acc[s][u], 0, 0, 0);
        __syncthreads();
    }

    float* Cb = sc + (size_t)z * 128 * S_;
    #pragma unroll
    for (int s = 0; s < 4; s++)
        #pragma unroll
        for (int u = 0; u < 2; u++) {
            const int col = nb * 128 + wave * 32 + u * 16 + mrow;
            #pragma unroll
            for (int reg = 0; reg < 4; reg++) {
                const int row = mb * 64 + s * 16 + quad * 4 + reg;
                Cb[(size_t)row * S_ + col] = 0.125f * acc[s][u][reg];
            }
        }
}

// ---------------------------------------------------------------------------
// token-select + softmax -> normalized P (bf16, packed per-s pair).
// Side jobs (each block also does its softmax):
//   bh <  256 : cat[:, :512] = bo
//   bh <  320 : o_attn = 0
//   bh <  832 : pre = bs   (must be re-armed AFTER state_trace(t-1) read it,
//                           BEFORE Ws-GEMM(t) atomicAdds — this slot is safe)
// ---------------------------------------------------------------------------
__global__ __launch_bounds__(256) void attn_soft(
    const float* __restrict__ sc,             // (16,128,2048)
    const int*   __restrict__ tokens,         // (B,S)
    ushort_t* __restrict__ P,                 // (8,128,4096)
    float* __restrict__ o,                    // (B,512) -> zeroed
    float* __restrict__ cat,                  // (B,2560)
    const float* __restrict__ bo,
    const float* __restrict__ bs,
    float* __restrict__ pre)                  // (B,4096) -> init to bs
{
    const int bh = blockIdx.x;
    const int b = bh >> 3, h = bh & 7;
    __shared__ float red[256];
    const int tid = threadIdx.x;

    if (bh < 256) {
        const int idx = bh * 256 + tid;
        cat[(size_t)(idx >> 9) * 2560 + (idx & 511)] = bo[idx & 511];
    } else if (bh < 320) {
        const int idx = (bh - 256) * 256 + tid;   // 0..16383
        *(float4*)&o[idx * 4] = make_float4(0.f, 0.f, 0.f, 0.f);
    } else if (bh < 832) {
        const int idx = (bh - 320) * 256 + tid;   // 0..131071 float4s
        const float4* bs4 = (const float4*)bs;
        ((float4*)pre)[idx] = bs4[idx & 1023];
    }

    const float* sc0 = sc + ((size_t)h * 128 + b) * S_;
    const float* sc1 = sc + ((size_t)(8 + h) * 128 + b) * S_;
    const int* trow = tokens + (size_t)b * S_;

    int tok[8]; float sel[8];
    float lmax = -1e30f;
    #pragma unroll
    for (int i = 0; i < 8; i++) {
        const int s = tid + i * 256;
        tok[i] = trow[s];
        sel[i] = tok[i] ? sc1[s] : sc0[s];
        lmax = fmaxf(lmax, sel[i]);
    }
    red[tid] = lmax; __syncthreads();
    for (int off = 128; off > 0; off >>= 1) {
        if (tid < off) red[tid] = fmaxf(red[tid], red[tid + off]);
        __syncthreads();
    }
    const float mx = red[0];
    __syncthreads();

    float e[8];
    float lsum = 0.f;
    #pragma unroll
    for (int i = 0; i < 8; i++) {
        e[i] = expf(sel[i] - mx);
        lsum += e[i];
    }
    red[tid] = lsum; __syncthreads();
    for (int off = 128; off > 0; off >>= 1) {
        if (tid < off) red[tid] += red[tid + off];
        __syncthreads();
    }
    const float inv = 1.f / red[0];

    ushort_t* Pb = P + ((size_t)h * 128 + b) * 4096;
    #pragma unroll
    for (int i = 0; i < 8; i++) {
        const int s = tid + i * 256;
        const unsigned p = (unsigned)f2bf(e[i] * inv);
        const unsigned word = tok[i] ? (p << 16) : p;
        *(unsigned*)&Pb[s * 2] = word;
    }
}

// ---------------------------------------------------------------------------
// PV via MFMA: o[b, h*64+d] += sum_k P[h][b][k] * VT[h][d][k], k=s*2+c (4096)
// grid = (2 mb, 8 h, 8 z). kchunk=512. atomicAdd into pre-zeroed o.
// ---------------------------------------------------------------------------
__global__ __launch_bounds__(256) void gemm_pv(
    const ushort_t* __restrict__ P,    // (8,128,4096)
    const ushort_t* __restrict__ VT,   // (8,64,4096)
    float* __restrict__ o)             // (128,512)
{
    const int mb = blockIdx.x, h = blockIdx.y, zb = blockIdx.z;
    const int k0 = zb * 512;
    __shared__ ushort_t As[64][40];
    __shared__ ushort_t Bs[64][40];

    const int tid  = threadIdx.x;
    const int wave = tid >> 6;
    const int lane = tid & 63;
    const int quad = lane >> 4;
    const int mrow = lane & 15;

    f32x4 acc[4];
    #pragma unroll
    for (int s = 0; s < 4; s++) acc[s] = (f32x4){0.f, 0.f, 0.f, 0.f};

    const int row = tid >> 2, kc = (tid & 3) * 8;
    const ushort_t* Ab = P  + ((size_t)h * 128 + mb * 64 + row) * 4096;
    const ushort_t* Bb = VT + ((size_t)h * 64 + row) * 4096;

    for (int kk = k0; kk < k0 + 512; kk += 32) {
        *(us8*)&As[row][kc] = *(const us8*)(Ab + kk + kc);
        *(us8*)&Bs[row][kc] = *(const us8*)(Bb + kk + kc);
        __syncthreads();
        bf16x8 bfr = *(const bf16x8*)&Bs[wave * 16 + mrow][quad * 8];
        #pragma unroll
        for (int s = 0; s < 4; s++) {
            bf16x8 af = *(const bf16x8*)&As[s * 16 + mrow][quad * 8];
            acc[s] = __builtin_amdgcn_mfma_f32_16x16x32_bf16(af, bfr, acc[s], 0, 0, 0);
        }
        __syncthreads();
    }

    const int col = h * 64 + wave * 16 + mrow;
    #pragma unroll
    for (int s = 0; s < 4; s++)
        #pragma unroll
        for (int reg = 0; reg < 4; reg++) {
            const int rowi = mb * 64 + s * 16 + quad * 4 + reg;
            atomicAdd(&o[(size_t)rowi * 512 + col], acc[s][reg]);
        }
}

// ---------------------------------------------------------------------------
// VT[h][d][s*2+c] = bf16(Vtab[(c*S+s)*512 + h*64+d])   (one-time)
// ---------------------------------------------------------------------------
__global__ void build_vt(const float* __restrict__ Vtab, ushort_t* __restrict__ VT)
{
    const int gid = blockIdx.x * 256 + threadIdx.x;  // 8*64*4096
    const int k = gid & 4095;
    const int d = (gid >> 12) & 63;
    const int h = gid >> 18;
    const int s = k >> 1, c = k & 1;
    VT[gid] = f2bf(Vtab[((size_t)(c * S_ + s)) * 512 + h * 64 + d]);
}

// ---------------------------------------------------------------------------
__global__ __launch_bounds__(256) void transpose_bf16_kernel(
    const float* __restrict__ in, ushort_t* __restrict__ out, int K, int N)
{
    __shared__ float tile[32][33];
    const int k0 = blockIdx.y * 32, n0 = blockIdx.x * 32;
    const int tx = threadIdx.x & 31, ty4 = (threadIdx.x >> 5) * 4;
    #pragma unroll
    for (int i = 0; i < 4; i++)
        tile[ty4 + i][tx] = in[(size_t)(k0 + ty4 + i) * N + n0 + tx];
    __syncthreads();
    #pragma unroll
    for (int i = 0; i < 4; i++)
        out[(size_t)(n0 + ty4 + i) * K + k0 + tx] = f2bf(tile[tx][ty4 + i]);
}

// ---------------------------------------------------------------------------
__global__ void cast_bf16_kernel(const float* __restrict__ src,
                                 __hip_bfloat16* __restrict__ dst, int n)
{
    const int gid = (blockIdx.x * 256 + threadIdx.x) * 4;
    if (gid >= n) return;
    float4 v = *(const float4*)(src + gid);
    dst[gid + 0] = __float2bfloat16(v.x);
    dst[gid + 1] = __float2bfloat16(v.y);
    dst[gid + 2] = __float2bfloat16(v.z);
    dst[gid + 3] = __float2bfloat16(v.w);
}

// ---------------------------------------------------------------------------
__global__ void feats_kernel(const float* __restrict__ emb,
                             const float* __restrict__ Wp,
                             const float* __restrict__ bp,
                             float* __restrict__ f2)
{
    const int gid = blockIdx.x * 256 + threadIdx.x;
    const int k = gid & 511;
    const int s = (gid >> 9) & (S_ - 1);
    const int c = gid >> 20;
    const float th = 3.14159265358979323846f * (float)s / (float)(S_ - 1);
    f2[gid] = emb[c * 512 + k] + (-sinf(th)) * Wp[k] + cosf(th) * Wp[512 + k] + bp[k];
}

__global__ void init_act_kernel(const float* __restrict__ sa,
                                float* __restrict__ act,
                                float* __restrict__ cat)
{
    const int gid = blockIdx.x * 256 + threadIdx.x;
    const int b = gid >> 11, n = gid & 2047;
    const float v = sa[n];
    act[gid] = v;
    cat[(size_t)b * 2560 + 512 + n] = v;
}

__global__ void init_trace_kernel(const float* __restrict__ st,
                                  float* __restrict__ trace)
{
    const int gid = blockIdx.x * 256 + threadIdx.x;
    trace[gid] = st[gid % (D_MODEL_ * M_)];
}

// ---------------------------------------------------------------------------
// sync: writes bf16 s_out. Block y==8 also initializes up to two bias
// buffers. Used ONCE (prologue, t=0 action-sync); later syncs are fused
// into state_trace_kernel.
// ---------------------------------------------------------------------------
__global__ void sync_kernel(const float* __restrict__ act,
                            float* __restrict__ alpha,
                            const float* __restrict__ decay,
                            const int t, const int off,
                            ushort_t* __restrict__ sout,
                            float* __restrict__ ib1, const float* __restrict__ bias1, int iN1,
                            float* __restrict__ ib2, const float* __restrict__ bias2, int iN2)
{
    const int b = blockIdx.x;
    const int tid = threadIdx.x;
    if (blockIdx.y == 8) {
        if (ib1)
            for (int n = tid; n < iN1; n += 256)
                ib1[(size_t)b * iN1 + n] = bias1[n];
        if (ib2)
            for (int n = tid; n < iN2; n += 256)
                ib2[(size_t)b * iN2 + n] = bias2[n];
    }
    const int p = blockIdx.y * 256 + tid;
    if (p >= REP_) return;
    int i = 0, rem = p;
    while (rem >= NSY_ - i) { rem -= NSY_ - i; i++; }
    const int j = i + rem;
    const float si = act[(size_t)b * D_MODEL_ + off + i];
    const float sj = act[(size_t)b * D_MODEL_ + off + j];
    const float pair = si * sj;
    const float r = expf(-decay[p]);
    float a;
    if (t == 0) a = pair;
    else        a = r * alpha[(size_t)b * REP_ + p] + pair;
    alpha[(size_t)b * REP_ + p] = a;
    float bta = 1.f;
    for (int k = 0; k < t; k++) bta = r * bta + 1.f;
    sout[(size_t)b * REP_ + p] = f2bf(a / sqrtf(bta));
}

// ---------------------------------------------------------------------------
// fused: state = LN(glu(pre)); CIRCULAR trace (write slot t, read slots
// (t+1+m)%25 in logical order -> bit-identical); Wn proj -> act, cat.
// Epilogues (fused former sync_kernel launches):
//   half==0 block: sync_out(t)  [act[b,0..63] from own regs] + predt=bout
//   half==1 block: sync_act(t+1)[act[b,1984..2047]]          + qbuf=bq
// grid = 256 blocks: (b, half).
// ---------------------------------------------------------------------------
__global__ __launch_bounds__(256) void state_trace_kernel(
    const float* __restrict__ pre,    // (B,4096)
    const float* __restrict__ g,
    const float* __restrict__ bt,
    float* __restrict__ trace,        // (B,2048,25) circular, head = t
    const float* __restrict__ ln_g,   // (25)
    const float* __restrict__ ln_b,   // (25)
    const float* __restrict__ Wn,     // (25,2,2048)
    const float* __restrict__ bn,     // (2048,2)
    const float* __restrict__ temp,   // (1)
    float* __restrict__ act,          // (B,2048)
    float* __restrict__ cat,          // (B,2560)
    const int t,
    const float* __restrict__ dec_out,
    float* __restrict__ a_o,
    ushort_t* __restrict__ s_outb,
    const float* __restrict__ bout,   // (4096)
    float* __restrict__ predt,        // (B,4096) slab for t
    const float* __restrict__ dec_act,
    float* __restrict__ a_a,
    ushort_t* __restrict__ s_actb,
    const float* __restrict__ bq,     // (512)
    float* __restrict__ qbuf,         // (B,512)
    const int do_act)
{
    const int b = blockIdx.x >> 1, half = blockIdx.x & 1;
    const int tid = threadIdx.x;
    __shared__ float v[D_MODEL_];
    __shared__ float r1[256], r2[256];
    __shared__ float sh_sync[64];
    float s1 = 0.f, s2 = 0.f;
    #pragma unroll
    for (int i = 0; i < 8; i++) {
        const int dd = tid + i * 256;
        const float g1 = pre[(size_t)b * 4096 + dd];
        const float g2 = pre[(size_t)b * 4096 + 2048 + dd];
        const float val = g1 * (1.f / (1.f + expf(-g2)));
        v[dd] = val; s1 += val; s2 += val * val;
    }
    r1[tid] = s1; r2[tid] = s2; __syncthreads();
    for (int off = 128; off > 0; off >>= 1) {
        if (tid < off) { r1[tid] += r1[tid + off]; r2[tid] += r2[tid + off]; }
        __syncthreads();
    }
    const float mu = r1[0] * (1.f / D_MODEL_);
    const float var = fmaxf(r2[0] * (1.f / D_MODEL_) - mu * mu, 0.f);
    const float sinv = 1.f / sqrtf(var + 1e-5f);
    const float tval = temp[0];

    #pragma unroll
    for (int i = 0; i < 4; i++) {
        const int n = half * 1024 + i * 256 + tid;
        const float sval = (v[n] - mu) * sinv * g[n] + bt[n];
        const int gid = b * 2048 + n;
        float* tr = trace + (size_t)gid * M_;
        float x[M_];
        // circular window: logical m -> physical slot (t+1+m) mod 25
        #pragma unroll
        for (int m = 0; m < M_ - 1; m++) {
            int slot = t + 1 + m;
            if (slot >= M_) slot -= M_;
            x[m] = tr[slot];
        }
        x[M_ - 1] = sval;
        tr[t] = sval;                 // single write instead of 25
        float t1 = 0.f, t2 = 0.f;
        #pragma unroll
        for (int m = 0; m < M_; m++) { t1 += x[m]; t2 += x[m] * x[m]; }
        const float tmu = t1 * (1.f / M_);
        const float tvar = fmaxf(t2 * (1.f / M_) - tmu * tmu, 0.f);
        const float tinv = 1.f / sqrtf(tvar + 1e-5f);
        float y0 = bn[n * 2 + 0], y1 = bn[n * 2 + 1];
        #pragma unroll
        for (int m = 0; m < M_; m++) {
            const float xn = (x[m] - tmu) * tinv * ln_g[m] + ln_b[m];
            y0 += xn * Wn[(size_t)(m * 2 + 0) * D_MODEL_ + n];
            y1 += xn * Wn[(size_t)(m * 2 + 1) * D_MODEL_ + n];
        }
        const float a = y0 * (1.f / (1.f + expf(-y1))) / tval;
        act[gid] = a;
        cat[(size_t)b * 2560 + 512 + n] = a;
        if (half == 0) {
            if (i == 0 && tid < 64) sh_sync[tid] = a;          // act[b, 0..63]
        } else {
            if (i == 3 && tid >= 192) sh_sync[tid - 192] = a;  // act[b, 1984..2047]
        }
    }
    __syncthreads();

    if (half == 0) {
        // --- fused sync_out(t), off=0 ---
        for (int p = tid; p < REP_; p += 256) {
            int ii = 0, rem = p;
            while (rem >= NSY_ - ii) { rem -= NSY_ - ii; ii++; }
            const int jj = ii + rem;
            const float pair = sh_sync[ii] * sh_sync[jj];
            const float r = expf(-dec_out[p]);
            float a2;
            if (t == 0) a2 = pair;
            else        a2 = r * a_o[(size_t)b * REP_ + p] + pair;
            a_o[(size_t)b * REP_ + p] = a2;
            float bta = 1.f;
            for (int k = 0; k < t; k++) bta = r * bta + 1.f;
            s_outb[(size_t)b * REP_ + p] = f2bf(a2 / sqrtf(bta));
        }
        // predt = bout (arm split-K atomic target for Wout-GEMM(t))
        const float4* b4 = (const float4*)bout;
        float4* pd = (float4*)(predt + (size_t)b * 4096);
        for (int idx = tid; idx < 1024; idx += 256) pd[idx] = b4[idx];
    } else if (do_act) {
        // --- fused sync_act(t+1), off=1984 ---
        const int tn = t + 1;
        for (int p = tid; p < REP_; p += 256) {
            int ii = 0, rem = p;
            while (rem >= NSY_ - ii) { rem -= NSY_ - ii; ii++; }
            const int jj = ii + rem;
            const float pair = sh_sync[ii] * sh_sync[jj];
            const float r = expf(-dec_act[p]);
            float a2 = r * a_a[(size_t)b * REP_ + p] + pair;   // tn >= 1 always
            a_a[(size_t)b * REP_ + p] = a2;
            float bta = 1.f;
            for (int k = 0; k < tn; k++) bta = r * bta + 1.f;
            s_actb[(size_t)b * REP_ + p] = f2bf(a2 / sqrtf(bta));
        }
        // qbuf = bq (arm split-K atomic target for q-GEMM(t+1))
        const float4* b4 = (const float4*)bq;
        float4* qb = (float4*)(qbuf + (size_t)b * 512);
        if (tid < 128) qb[tid] = b4[tid];
    }
}

// ---------------------------------------------------------------------------
// Batched entropy over ALL T slabs — runs once after the loop (ent feeds
// nothing inside the loop). grid = T*B blocks.
// ---------------------------------------------------------------------------
__global__ __launch_bounds__(256) void ent_all_kernel(
    const float* __restrict__ predst,  // (T, B*4096)
    float* __restrict__ certbf)        // (T, B*2)
{
    const int t = blockIdx.x >> 7;
    const int b = blockIdx.x & 127;
    const int tid = threadIdx.x;
    __shared__ float red[256];
    const float* pr = predst + (size_t)t * PRED_N + (size_t)b * 4096;
    float sum = 0.f;
    #pragma unroll
    for (int i = 0; i < 8; i++) {
        const int s = tid + i * 256;
        const float l0 = pr[2 * s], l1 = pr[2 * s + 1];
        const float mm = fmaxf(l0, l1);
        const float z0 = expf(l0 - mm), z1 = expf(l1 - mm);
        const float Z = z0 + z1;
        const float lz = logf(Z);
        const float p0 = z0 / Z, p1 = z1 / Z;
        const float lp0 = (l0 - mm) - lz, lp1 = (l1 - mm) - lz;
        sum += -(p0 * lp0 + p1 * lp1) * 1.4426950408889634f;
    }
    red[tid] = sum; __syncthreads();
    for (int off = 128; off > 0; off >>= 1) {
        if (tid < off) red[tid] += red[tid + off];
        __syncthreads();
    }
    if (tid == 0) {
        const float ne = red[0] * (1.f / S_);
        certbf[(size_t)t * B_ * 2 + b * 2 + 0] = ne;
        certbf[(size_t)t * B_ * 2 + b * 2 + 1] = 1.f - ne;
    }
}

// ---------------------------------------------------------------------------
__global__ __launch_bounds__(256) void finalize_kernel(
    const float* __restrict__ predstage,  // (T, B*4096)
    const float* __restrict__ certbuf,    // (T, B*2)
    float* __restrict__ dout)
{
    __shared__ float tile[T_][1024];
    const int tid = threadIdx.x;
    const int row0 = blockIdx.x * 1024;
    #pragma unroll
    for (int t = 0; t < T_; t++) {
        float4 v = *(const float4*)(predstage + (size_t)t * PRED_N + row0 + tid * 4);
        tile[t][tid * 4 + 0] = v.x; tile[t][tid * 4 + 1] = v.y;
        tile[t][tid * 4 + 2] = v.z; tile[t][tid * 4 + 3] = v.w;
    }
    __syncthreads();
    float buf[40];
    #pragma unroll
    for (int r = 0; r < 4; r++)
        #pragma unroll
        for (int t = 0; t < T_; t++)
            buf[r * 10 + t] = tile[t][tid * 4 + r];
    float* dst = dout + (size_t)(row0 + tid * 4) * T_;
    #pragma unroll
    for (int k = 0; k < 10; k++)
        *(float4*)(dst + k * 4) = make_float4(buf[4*k], buf[4*k+1], buf[4*k+2], buf[4*k+3]);

    if (blockIdx.x == 0 && tid < B_) {
        const int b = tid;
        const size_t base = (size_t)PRED_N * T_;
        #pragma unroll
        for (int t = 0; t < T_; t++) {
            dout[base + (size_t)(b * 2 + 0) * T_ + t] = certbuf[t * B_ * 2 + b * 2 + 0];
            dout[base + (size_t)(b * 2 + 1) * T_ + t] = certbuf[t * B_ * 2 + b * 2 + 1];
        }
    }
}

// ---------------------------------------------------------------------------
extern "C" void kernel_launch(void* const* d_in, const int* in_sizes, int n_in,
                              void* d_out, int out_size, void* d_ws, size_t ws_size,
                              hipStream_t stream)
{
    const int*   tokens    = (const int*)  d_in[0];
    const float* emb       = (const float*)d_in[1];
    const float* W_pos     = (const float*)d_in[2];
    const float* b_pos     = (const float*)d_in[3];
    const float* Wq        = (const float*)d_in[4];
    const float* bq        = (const float*)d_in[5];
    const float* Wk        = (const float*)d_in[6];
    const float* bk        = (const float*)d_in[7];
    const float* Wv        = (const float*)d_in[8];
    const float* bv        = (const float*)d_in[9];
    const float* Wo        = (const float*)d_in[10];
    const float* bo        = (const float*)d_in[11];
    const float* Ws        = (const float*)d_in[12];
    const float* bs        = (const float*)d_in[13];
    const float* ln_s_g    = (const float*)d_in[14];
    const float* ln_s_b    = (const float*)d_in[15];
    const float* ln_n_g    = (const float*)d_in[16];
    const float* ln_n_b    = (const float*)d_in[17];
    const float* Wn        = (const float*)d_in[18];
    const float* bn        = (const float*)d_in[19];
    const float* temp      = (const float*)d_in[20];
    const float* Wout      = (const float*)d_in[21];
    const float* bout      = (const float*)d_in[22];
    const float* start_act = (const float*)d_in[23];
    const float* start_tr  = (const float*)d_in[24];
    const float* dec_act   = (const float*)d_in[25];
    const float* dec_out   = (const float*)d_in[26];
    float* out = (float*)d_out;
    float* w = (float*)d_ws;

    // workspace layout (floats)
    size_t off = 0;
    float* f2     = w + off; off += (size_t)2 * S_ * 512;
    float* Ktab   = w + off; off += (size_t)2 * S_ * 512;
    float* Vtab   = w + off; off += (size_t)2 * S_ * 512;
    float* act    = w + off; off += (size_t)B_ * D_MODEL_;
    float* cat    = w + off; off += (size_t)B_ * 2560;
    float* a_a    = w + off; off += (size_t)B_ * REP_;
    float* a_o    = w + off; off += (size_t)B_ * REP_;
    float* qbuf   = w + off; off += (size_t)B_ * 512;
    float* o_attn = w + off; off += (size_t)B_ * 512;
    float* pre    = w + off; off += (size_t)B_ * 4096;
    float* trace  = w + off; off += (size_t)B_ * D_MODEL_ * M_;
    float* scbuf  = w + off; off += (size_t)16 * 128 * S_;
    float* predst = w + off; off += (size_t)T_ * PRED_N;     // (T, B*4096)
    float* certbf = w + off; off += (size_t)T_ * B_ * 2;
    ushort_t* s_actb = (ushort_t*)(w + off); off += (size_t)B_ * REP_ / 2;
    ushort_t* s_outb = (ushort_t*)(w + off); off += (size_t)B_ * REP_ / 2;
    __hip_bfloat16* Kb = (__hip_bfloat16*)(w + off); off += (size_t)S_ * 512;
    ushort_t* Pbuf  = (ushort_t*)(w + off); off += (size_t)8 * 128 * 4096 / 2;
    ushort_t* VT    = (ushort_t*)(w + off); off += (size_t)8 * 64 * 4096 / 2;
    ushort_t* WkT   = (ushort_t*)(w + off); off += (size_t)512 * 512 / 2;
    ushort_t* WvT   = (ushort_t*)(w + off); off += (size_t)512 * 512 / 2;
    ushort_t* WqT   = (ushort_t*)(w + off); off += (size_t)512 * REP_ / 2;
    ushort_t* WoT   = (ushort_t*)(w + off); off += (size_t)512 * 512 / 2;
    ushort_t* WsT   = (ushort_t*)(w + off); off += (size_t)4096 * 2560 / 2;
    ushort_t* WoutT = (ushort_t*)(w + off); off += (size_t)4096 * REP_ / 2;

    // ---- pre-loop ----
    feats_kernel<<<(2 * S_ * 512) / 256, 256, 0, stream>>>(emb, W_pos, b_pos, f2);
    init_act_kernel<<<(B_ * D_MODEL_) / 256, 256, 0, stream>>>(start_act, act, cat);
    init_trace_kernel<<<(B_ * D_MODEL_ * M_) / 256, 256, 0, stream>>>(start_tr, trace);

    transpose_bf16_kernel<<<dim3(512 / 32, 512 / 32), 256, 0, stream>>>(Wk, WkT, 512, 512);
    transpose_bf16_kernel<<<dim3(512 / 32, 512 / 32), 256, 0, stream>>>(Wv, WvT, 512, 512);
    transpose_bf16_kernel<<<dim3(512 / 32, REP_ / 32), 256, 0, stream>>>(Wq, WqT, REP_, 512);
    transpose_bf16_kernel<<<dim3(512 / 32, 512 / 32), 256, 0, stream>>>(Wo, WoT, 512, 512);
    transpose_bf16_kernel<<<dim3(4096 / 32, 2560 / 32), 256, 0, stream>>>(Ws, WsT, 2560, 4096);
    transpose_bf16_kernel<<<dim3(4096 / 32, REP_ / 32), 256, 0, stream>>>(Wout, WoutT, REP_, 4096);

    gemm_bf16<<<dim3(512 / 128, (2 * S_) / 64, 1), 256, 0, stream>>>(
        f2, 512, WkT, 512, bk, Ktab, 512, 2 * S_, 512, 512, 512);
    gemm_bf16<<<dim3(512 / 128, (2 * S_) / 64, 1), 256, 0, stream>>>(
        f2, 512, WvT, 512, bv, Vtab, 512, 2 * S_, 512, 512, 512);
    cast_bf16_kernel<<<(2 * S_ * 512 / 4) / 256, 256, 0, stream>>>(Ktab, Kb, 2 * S_ * 512);
    build_vt<<<(8 * 64 * 4096) / 256, 256, 0, stream>>>(Vtab, VT);

    // t=0 action-sync (from init act); y==8 block inits qbuf=bq
    sync_kernel<<<dim3(B_, 9), 256, 0, stream>>>(
        act, a_a, dec_act, 0, D_MODEL_ - NSY_, s_actb,
        qbuf, bq, 512, nullptr, nullptr, 0);
    // q-GEMM(0)
    gemm_bb<<<dim3(512 / 128, 2, 13), 256, 0, stream>>>(
        s_actb, REP_, WqT, REP_, bq, qbuf, 512, B_, 512, REP_, 160);

    // ---- T iterations (7 launches each; syncs/ent fused or hoisted) ----
    for (int t = 0; t < T_; t++) {
        gemm_qk<<<dim3(S_ / 128, 2, 16), 256, 0, stream>>>(
            qbuf, (const ushort_t*)Kb, scbuf);
        // attn_soft also re-arms pre=bs (blocks 320..831) for Ws-GEMM(t)
        attn_soft<<<B_ * H_, 256, 0, stream>>>(
            scbuf, tokens, Pbuf, o_attn, cat, bo, bs, pre);
        gemm_pv<<<dim3(2, 8, 8), 256, 0, stream>>>(Pbuf, VT, o_attn);

        gemm_bf16<<<dim3(512 / 128, 2, 8), 256, 0, stream>>>(
            o_attn, 512, WoT, 512, bo, cat, 2560, B_, 512, 512, 64);

        gemm_bf16<<<dim3(4096 / 128, 2, 8), 256, 0, stream>>>(
            cat, 2560, WsT, 2560, bs, pre, 4096, B_, 4096, 2560, 320);

        float* predt = predst + (size_t)t * PRED_N;
        // fused: state/trace/act + sync_out(t) + predt=bout + sync_act(t+1) + qbuf=bq
        state_trace_kernel<<<B_ * 2, 256, 0, stream>>>(
            pre, ln_s_g, ln_s_b, trace, ln_n_g, ln_n_b, Wn, bn, temp, act, cat,
            t, dec_out, a_o, s_outb, bout, predt,
            dec_act, a_a, s_actb, bq, qbuf, (t < T_ - 1) ? 1 : 0);

        // merged: Wout-GEMM(t) [320 blocks] + q-GEMM(t+1) [104 blocks, skip at t=9]
        const int blocks2 = (t < T_ - 1) ? 104 : 0;
        gemm_bb_dual<<<dim3(320 + blocks2), 256, 0, stream>>>(
            s_outb, REP_, WoutT, REP_, predt, 4096, 416, 32, 320,
            s_actb, REP_, WqT, REP_, qbuf, 512, 160, 4);
    }

    // batched entropy (all t at once), then the coalesced output pass
    ent_all_kernel<<<T_ * B_, 256, 0, stream>>>(predst, certbf);
    finalize_kernel<<<PRED_N / 1024, 256, 0, stream>>>(predst, certbf, out);
}

// Round 2
// 1216.411 us; speedup vs baseline: 1.3241x; 1.3241x over previous
//
#include <hip/hip_runtime.h>
#include <hip/hip_bf16.h>
#include <math.h>

#define B_ 128
#define S_ 2048
#define D_IN_ 512
#define D_MODEL_ 2048
#define M_ 25
#define NSY_ 64
#define H_ 8
#define T_ 10
#define REP_ 2080
#define DH_ 64
#define PRED_N (B_ * 4096)

typedef unsigned short ushort_t;
typedef __bf16 bf16x8 __attribute__((ext_vector_type(8)));
typedef float f32x4 __attribute__((ext_vector_type(4)));
typedef unsigned short us8 __attribute__((ext_vector_type(8)));

__device__ __forceinline__ ushort_t f2bf(float f) {
    __hip_bfloat16 h = __float2bfloat16(f);
    return *(ushort_t*)&h;
}

// ---------------------------------------------------------------------------
// MFMA bf16 GEMM, f32 A (cast during staging): C[M,N] (+)= A @ Bt^T
// grid = (N/128, M/64, Z). Z==1: direct store + bias. Z>1: atomicAdd.
// ---------------------------------------------------------------------------
__global__ __launch_bounds__(256) void gemm_bf16(
    const float* __restrict__ A, int lda,
    const ushort_t* __restrict__ Bt, int ldb,
    const float* __restrict__ bias,
    float* __restrict__ C, int ldc,
    int M, int N, int K, int kchunk)
{
    const int nb = blockIdx.x, mb = blockIdx.y, zb = blockIdx.z;
    const int k0 = zb * kchunk;
    const int k1 = min(K, k0 + kchunk);
    __shared__ ushort_t As[64][40];
    __shared__ ushort_t Bs[128][40];

    const int tid  = threadIdx.x;
    const int wave = tid >> 6;
    const int lane = tid & 63;
    const int quad = lane >> 4;
    const int mrow = lane & 15;

    f32x4 acc[4][2];
    #pragma unroll
    for (int s = 0; s < 4; s++)
        #pragma unroll
        for (int u = 0; u < 2; u++)
            acc[s][u] = (f32x4){0.f, 0.f, 0.f, 0.f};

    const int arow = tid >> 2, akc = (tid & 3) * 8;
    const int brow = tid >> 1, bkc = (tid & 1) * 16;

    for (int kk0 = k0; kk0 < k1; kk0 += 32) {
        {
            const float* ap = A + (size_t)(mb * 64 + arow) * lda + kk0 + akc;
            float4 v0 = *(const float4*)ap;
            float4 v1 = *(const float4*)(ap + 4);
            us8 w = { f2bf(v0.x), f2bf(v0.y), f2bf(v0.z), f2bf(v0.w),
                      f2bf(v1.x), f2bf(v1.y), f2bf(v1.z), f2bf(v1.w) };
            *(us8*)&As[arow][akc] = w;
        }
        {
            const ushort_t* bp = Bt + (size_t)(nb * 128 + brow) * ldb + kk0 + bkc;
            *(us8*)&Bs[brow][bkc]     = *(const us8*)bp;
            *(us8*)&Bs[brow][bkc + 8] = *(const us8*)(bp + 8);
        }
        __syncthreads();

        bf16x8 af[4], bfr[2];
        #pragma unroll
        for (int s = 0; s < 4; s++)
            af[s] = *(const bf16x8*)&As[s * 16 + mrow][quad * 8];
        #pragma unroll
        for (int u = 0; u < 2; u++)
            bfr[u] = *(const bf16x8*)&Bs[wave * 32 + u * 16 + mrow][quad * 8];
        #pragma unroll
        for (int s = 0; s < 4; s++)
            #pragma unroll
            for (int u = 0; u < 2; u++)
                acc[s][u] = __builtin_amdgcn_mfma_f32_16x16x32_bf16(
                    af[s], bfr[u], acc[s][u], 0, 0, 0);
        __syncthreads();
    }

    if (gridDim.z == 1) {
        #pragma unroll
        for (int s = 0; s < 4; s++)
            #pragma unroll
            for (int u = 0; u < 2; u++) {
                const int col = nb * 128 + wave * 32 + u * 16 + mrow;
                #pragma unroll
                for (int reg = 0; reg < 4; reg++) {
                    const int row = mb * 64 + s * 16 + quad * 4 + reg;
                    C[(size_t)row * ldc + col] = acc[s][u][reg] + bias[col];
                }
            }
    } else {
        #pragma unroll
        for (int s = 0; s < 4; s++)
            #pragma unroll
            for (int u = 0; u < 2; u++) {
                const int col = nb * 128 + wave * 32 + u * 16 + mrow;
                #pragma unroll
                for (int reg = 0; reg < 4; reg++) {
                    const int row = mb * 64 + s * 16 + quad * 4 + reg;
                    atomicAdd(&C[(size_t)row * ldc + col], acc[s][u][reg]);
                }
            }
    }
}

// ---------------------------------------------------------------------------
// Same GEMM but A already bf16 (pure-copy staging). Used for q(0) prologue.
// ---------------------------------------------------------------------------
__global__ __launch_bounds__(256) void gemm_bb(
    const ushort_t* __restrict__ A, int lda,
    const ushort_t* __restrict__ Bt, int ldb,
    const float* __restrict__ bias,
    float* __restrict__ C, int ldc,
    int M, int N, int K, int kchunk)
{
    const int nb = blockIdx.x, mb = blockIdx.y, zb = blockIdx.z;
    const int k0 = zb * kchunk;
    const int k1 = min(K, k0 + kchunk);
    __shared__ ushort_t As[64][40];
    __shared__ ushort_t Bs[128][40];

    const int tid  = threadIdx.x;
    const int wave = tid >> 6;
    const int lane = tid & 63;
    const int quad = lane >> 4;
    const int mrow = lane & 15;

    f32x4 acc[4][2];
    #pragma unroll
    for (int s = 0; s < 4; s++)
        #pragma unroll
        for (int u = 0; u < 2; u++)
            acc[s][u] = (f32x4){0.f, 0.f, 0.f, 0.f};

    const int arow = tid >> 2, akc = (tid & 3) * 8;
    const int brow = tid >> 1, bkc = (tid & 1) * 16;

    for (int kk0 = k0; kk0 < k1; kk0 += 32) {
        {
            const ushort_t* ap = A + (size_t)(mb * 64 + arow) * lda + kk0 + akc;
            *(us8*)&As[arow][akc] = *(const us8*)ap;
        }
        {
            const ushort_t* bp = Bt + (size_t)(nb * 128 + brow) * ldb + kk0 + bkc;
            *(us8*)&Bs[brow][bkc]     = *(const us8*)bp;
            *(us8*)&Bs[brow][bkc + 8] = *(const us8*)(bp + 8);
        }
        __syncthreads();

        bf16x8 af[4], bfr[2];
        #pragma unroll
        for (int s = 0; s < 4; s++)
            af[s] = *(const bf16x8*)&As[s * 16 + mrow][quad * 8];
        #pragma unroll
        for (int u = 0; u < 2; u++)
            bfr[u] = *(const bf16x8*)&Bs[wave * 32 + u * 16 + mrow][quad * 8];
        #pragma unroll
        for (int s = 0; s < 4; s++)
            #pragma unroll
            for (int u = 0; u < 2; u++)
                acc[s][u] = __builtin_amdgcn_mfma_f32_16x16x32_bf16(
                    af[s], bfr[u], acc[s][u], 0, 0, 0);
        __syncthreads();
    }

    if (gridDim.z == 1) {
        #pragma unroll
        for (int s = 0; s < 4; s++)
            #pragma unroll
            for (int u = 0; u < 2; u++) {
                const int col = nb * 128 + wave * 32 + u * 16 + mrow;
                #pragma unroll
                for (int reg = 0; reg < 4; reg++) {
                    const int row = mb * 64 + s * 16 + quad * 4 + reg;
                    C[(size_t)row * ldc + col] = acc[s][u][reg] + bias[col];
                }
            }
    } else {
        #pragma unroll
        for (int s = 0; s < 4; s++)
            #pragma unroll
            for (int u = 0; u < 2; u++) {
                const int col = nb * 128 + wave * 32 + u * 16 + mrow;
                #pragma unroll
                for (int reg = 0; reg < 4; reg++) {
                    const int row = mb * 64 + s * 16 + quad * 4 + reg;
                    atomicAdd(&C[(size_t)row * ldc + col], acc[s][u][reg]);
                }
            }
    }
}

// ---------------------------------------------------------------------------
// Dual bf16-A GEMM (both K=REP_, M=128, atomic epilogue): one launch runs
// Wout-GEMM(t) [blocks < nblk1] and q-GEMM(t+1) [blocks >= nblk1].
// ---------------------------------------------------------------------------
__global__ __launch_bounds__(256) void gemm_bb_dual(
    const ushort_t* __restrict__ A1, int lda1,
    const ushort_t* __restrict__ Bt1, int ldb1,
    float* __restrict__ C1, int ldc1, int kc1, int nb1x, int nblk1,
    const ushort_t* __restrict__ A2, int lda2,
    const ushort_t* __restrict__ Bt2, int ldb2,
    float* __restrict__ C2, int ldc2, int kc2, int nb2x)
{
    int bid = blockIdx.x;
    const ushort_t* A; const ushort_t* Bt; float* C;
    int lda, ldb, ldc, nb, mb, zb, kchunk;
    if (bid < nblk1) {
        A = A1; Bt = Bt1; C = C1; lda = lda1; ldb = ldb1; ldc = ldc1; kchunk = kc1;
        nb = bid % nb1x; mb = (bid / nb1x) & 1; zb = bid / (nb1x * 2);
    } else {
        bid -= nblk1;
        A = A2; Bt = Bt2; C = C2; lda = lda2; ldb = ldb2; ldc = ldc2; kchunk = kc2;
        nb = bid % nb2x; mb = (bid / nb2x) & 1; zb = bid / (nb2x * 2);
    }
    const int k0 = zb * kchunk;
    const int k1 = min(REP_, k0 + kchunk);
    __shared__ ushort_t As[64][40];
    __shared__ ushort_t Bs[128][40];

    const int tid  = threadIdx.x;
    const int wave = tid >> 6;
    const int lane = tid & 63;
    const int quad = lane >> 4;
    const int mrow = lane & 15;

    f32x4 acc[4][2];
    #pragma unroll
    for (int s = 0; s < 4; s++)
        #pragma unroll
        for (int u = 0; u < 2; u++)
            acc[s][u] = (f32x4){0.f, 0.f, 0.f, 0.f};

    const int arow = tid >> 2, akc = (tid & 3) * 8;
    const int brow = tid >> 1, bkc = (tid & 1) * 16;

    for (int kk0 = k0; kk0 < k1; kk0 += 32) {
        {
            const ushort_t* ap = A + (size_t)(mb * 64 + arow) * lda + kk0 + akc;
            *(us8*)&As[arow][akc] = *(const us8*)ap;
        }
        {
            const ushort_t* bp = Bt + (size_t)(nb * 128 + brow) * ldb + kk0 + bkc;
            *(us8*)&Bs[brow][bkc]     = *(const us8*)bp;
            *(us8*)&Bs[brow][bkc + 8] = *(const us8*)(bp + 8);
        }
        __syncthreads();

        bf16x8 af[4], bfr[2];
        #pragma unroll
        for (int s = 0; s < 4; s++)
            af[s] = *(const bf16x8*)&As[s * 16 + mrow][quad * 8];
        #pragma unroll
        for (int u = 0; u < 2; u++)
            bfr[u] = *(const bf16x8*)&Bs[wave * 32 + u * 16 + mrow][quad * 8];
        #pragma unroll
        for (int s = 0; s < 4; s++)
            #pragma unroll
            for (int u = 0; u < 2; u++)
                acc[s][u] = __builtin_amdgcn_mfma_f32_16x16x32_bf16(
                    af[s], bfr[u], acc[s][u], 0, 0, 0);
        __syncthreads();
    }

    #pragma unroll
    for (int s = 0; s < 4; s++)
        #pragma unroll
        for (int u = 0; u < 2; u++) {
            const int col = nb * 128 + wave * 32 + u * 16 + mrow;
            #pragma unroll
            for (int reg = 0; reg < 4; reg++) {
                const int row = mb * 64 + s * 16 + quad * 4 + reg;
                atomicAdd(&C[(size_t)row * ldc + col], acc[s][u][reg]);
            }
        }
}

// ---------------------------------------------------------------------------
// QK scores, dense both-token: sc[(c*8+h)*128+b][s] = 0.125 * q_bh . K_chs
// grid = (S/128, B/64, 16)
// ---------------------------------------------------------------------------
__global__ __launch_bounds__(256) void gemm_qk(
    const float* __restrict__ q,
    const ushort_t* __restrict__ Kb,
    float* __restrict__ sc)
{
    const int nb = blockIdx.x, mb = blockIdx.y, z = blockIdx.z;
    const int c = z >> 3, h = z & 7;
    __shared__ ushort_t As[64][40];
    __shared__ ushort_t Bs[128][40];

    const int tid  = threadIdx.x;
    const int wave = tid >> 6;
    const int lane = tid & 63;
    const int quad = lane >> 4;
    const int mrow = lane & 15;

    f32x4 acc[4][2];
    #pragma unroll
    for (int s = 0; s < 4; s++)
        #pragma unroll
        for (int u = 0; u < 2; u++)
            acc[s][u] = (f32x4){0.f, 0.f, 0.f, 0.f};

    const int arow = tid >> 2, akc = (tid & 3) * 8;
    const int brow = tid >> 1, bkc = (tid & 1) * 16;
    const float* Abase = q + (size_t)h * 64;
    const ushort_t* Bbase = Kb + (size_t)c * S_ * 512 + h * 64;

    #pragma unroll
    for (int kk0 = 0; kk0 < 64; kk0 += 32) {
        {
            const float* ap = Abase + (size_t)(mb * 64 + arow) * 512 + kk0 + akc;
            float4 v0 = *(const float4*)ap;
            float4 v1 = *(const float4*)(ap + 4);
            us8 w = { f2bf(v0.x), f2bf(v0.y), f2bf(v0.z), f2bf(v0.w),
                      f2bf(v1.x), f2bf(v1.y), f2bf(v1.z), f2bf(v1.w) };
            *(us8*)&As[arow][akc] = w;
        }
        {
            const ushort_t* bp = Bbase + (size_t)(nb * 128 + brow) * 512 + kk0 + bkc;
            *(us8*)&Bs[brow][bkc]     = *(const us8*)bp;
            *(us8*)&Bs[brow][bkc + 8] = *(const us8*)(bp + 8);
        }
        __syncthreads();

        bf16x8 af[4], bfr[2];
        #pragma unroll
        for (int s = 0; s < 4; s++)
            af[s] = *(const bf16x8*)&As[s * 16 + mrow][quad * 8];
        #pragma unroll
        for (int u = 0; u < 2; u++)
            bfr[u] = *(const bf16x8*)&Bs[wave * 32 + u * 16 + mrow][quad * 8];
        #pragma unroll
        for (int s = 0; s < 4; s++)
            #pragma unroll
            for (int u = 0; u < 2; u++)
                acc[s][u] = __builtin_amdgcn_mfma_f32_16x16x32_bf16(
                    af[s], bfr[u], acc[s][u], 0, 0, 0);
        __syncthreads();
    }

    float* Cb = sc + (size_t)z * 128 * S_;
    #pragma unroll
    for (int s = 0; s < 4; s++)
        #pragma unroll
        for (int u = 0; u < 2; u++) {
            const int col = nb * 128 + wave * 32 + u * 16 + mrow;
            #pragma unroll
            for (int reg = 0; reg < 4; reg++) {
                const int row = mb * 64 + s * 16 + quad * 4 + reg;
                Cb[(size_t)row * S_ + col] = 0.125f * acc[s][u][reg];
            }
        }
}

// ---------------------------------------------------------------------------
// token-select + softmax -> normalized P (bf16, packed per-s pair).
// Side jobs: bh<256: cat[:,:512]=bo; bh<320: o_attn=0; bh<832: pre=bs.
// ---------------------------------------------------------------------------
__global__ __launch_bounds__(256) void attn_soft(
    const float* __restrict__ sc,             // (16,128,2048)
    const int*   __restrict__ tokens,         // (B,S)
    ushort_t* __restrict__ P,                 // (8,128,4096)
    float* __restrict__ o,                    // (B,512) -> zeroed
    float* __restrict__ cat,                  // (B,2560)
    const float* __restrict__ bo,
    const float* __restrict__ bs,
    float* __restrict__ pre)                  // (B,4096) -> init to bs
{
    const int bh = blockIdx.x;
    const int b = bh >> 3, h = bh & 7;
    __shared__ float red[256];
    const int tid = threadIdx.x;

    if (bh < 256) {
        const int idx = bh * 256 + tid;
        cat[(size_t)(idx >> 9) * 2560 + (idx & 511)] = bo[idx & 511];
    } else if (bh < 320) {
        const int idx = (bh - 256) * 256 + tid;   // 0..16383
        *(float4*)&o[idx * 4] = make_float4(0.f, 0.f, 0.f, 0.f);
    } else if (bh < 832) {
        const int idx = (bh - 320) * 256 + tid;   // 0..131071 float4s
        const float4* bs4 = (const float4*)bs;
        ((float4*)pre)[idx] = bs4[idx & 1023];
    }

    const float* sc0 = sc + ((size_t)h * 128 + b) * S_;
    const float* sc1 = sc + ((size_t)(8 + h) * 128 + b) * S_;
    const int* trow = tokens + (size_t)b * S_;

    int tok[8]; float sel[8];
    float lmax = -1e30f;
    #pragma unroll
    for (int i = 0; i < 8; i++) {
        const int s = tid + i * 256;
        tok[i] = trow[s];
        sel[i] = tok[i] ? sc1[s] : sc0[s];
        lmax = fmaxf(lmax, sel[i]);
    }
    red[tid] = lmax; __syncthreads();
    for (int off = 128; off > 0; off >>= 1) {
        if (tid < off) red[tid] = fmaxf(red[tid], red[tid + off]);
        __syncthreads();
    }
    const float mx = red[0];
    __syncthreads();

    float e[8];
    float lsum = 0.f;
    #pragma unroll
    for (int i = 0; i < 8; i++) {
        e[i] = expf(sel[i] - mx);
        lsum += e[i];
    }
    red[tid] = lsum; __syncthreads();
    for (int off = 128; off > 0; off >>= 1) {
        if (tid < off) red[tid] += red[tid + off];
        __syncthreads();
    }
    const float inv = 1.f / red[0];

    ushort_t* Pb = P + ((size_t)h * 128 + b) * 4096;
    #pragma unroll
    for (int i = 0; i < 8; i++) {
        const int s = tid + i * 256;
        const unsigned p = (unsigned)f2bf(e[i] * inv);
        const unsigned word = tok[i] ? (p << 16) : p;
        *(unsigned*)&Pb[s * 2] = word;
    }
}

// ---------------------------------------------------------------------------
// PV via MFMA: o[b, h*64+d] += sum_k P[h][b][k] * VT[h][d][k], k=s*2+c (4096)
// grid = (2 mb, 8 h, 8 z). kchunk=512. atomicAdd into pre-zeroed o.
// ---------------------------------------------------------------------------
__global__ __launch_bounds__(256) void gemm_pv(
    const ushort_t* __restrict__ P,    // (8,128,4096)
    const ushort_t* __restrict__ VT,   // (8,64,4096)
    float* __restrict__ o)             // (128,512)
{
    const int mb = blockIdx.x, h = blockIdx.y, zb = blockIdx.z;
    const int k0 = zb * 512;
    __shared__ ushort_t As[64][40];
    __shared__ ushort_t Bs[64][40];

    const int tid  = threadIdx.x;
    const int wave = tid >> 6;
    const int lane = tid & 63;
    const int quad = lane >> 4;
    const int mrow = lane & 15;

    f32x4 acc[4];
    #pragma unroll
    for (int s = 0; s < 4; s++) acc[s] = (f32x4){0.f, 0.f, 0.f, 0.f};

    const int row = tid >> 2, kc = (tid & 3) * 8;
    const ushort_t* Ab = P  + ((size_t)h * 128 + mb * 64 + row) * 4096;
    const ushort_t* Bb = VT + ((size_t)h * 64 + row) * 4096;

    for (int kk = k0; kk < k0 + 512; kk += 32) {
        *(us8*)&As[row][kc] = *(const us8*)(Ab + kk + kc);
        *(us8*)&Bs[row][kc] = *(const us8*)(Bb + kk + kc);
        __syncthreads();
        bf16x8 bfr = *(const bf16x8*)&Bs[wave * 16 + mrow][quad * 8];
        #pragma unroll
        for (int s = 0; s < 4; s++) {
            bf16x8 af = *(const bf16x8*)&As[s * 16 + mrow][quad * 8];
            acc[s] = __builtin_amdgcn_mfma_f32_16x16x32_bf16(af, bfr, acc[s], 0, 0, 0);
        }
        __syncthreads();
    }

    const int col = h * 64 + wave * 16 + mrow;
    #pragma unroll
    for (int s = 0; s < 4; s++)
        #pragma unroll
        for (int reg = 0; reg < 4; reg++) {
            const int rowi = mb * 64 + s * 16 + quad * 4 + reg;
            atomicAdd(&o[(size_t)rowi * 512 + col], acc[s][reg]);
        }
}

// ---------------------------------------------------------------------------
// VT[h][d][s*2+c] = bf16(Vtab[(c*S+s)*512 + h*64+d])   (one-time)
// ---------------------------------------------------------------------------
__global__ void build_vt(const float* __restrict__ Vtab, ushort_t* __restrict__ VT)
{
    const int gid = blockIdx.x * 256 + threadIdx.x;  // 8*64*4096
    const int k = gid & 4095;
    const int d = (gid >> 12) & 63;
    const int h = gid >> 18;
    const int s = k >> 1, c = k & 1;
    VT[gid] = f2bf(Vtab[((size_t)(c * S_ + s)) * 512 + h * 64 + d]);
}

// ---------------------------------------------------------------------------
// Sync tables (one-time): pair decode ij, r = exp(-decay), sqrt(beta_t).
// Arithmetic identical to the former in-kernel computation (same expf,
// same bta recurrence, same sqrtf) so downstream division is bit-identical.
// ---------------------------------------------------------------------------
__global__ void build_sync_tabs(const float* __restrict__ dec_act,
                                const float* __restrict__ dec_out,
                                int* __restrict__ ijtab,
                                float* __restrict__ r_act,
                                float* __restrict__ r_out,
                                float* __restrict__ sqb_act,
                                float* __restrict__ sqb_out)
{
    const int p = blockIdx.x * 256 + threadIdx.x;
    if (p >= REP_) return;
    int i = 0, rem = p;
    while (rem >= NSY_ - i) { rem -= NSY_ - i; i++; }
    ijtab[p] = (i << 16) | (i + rem);
    const float ra = expf(-dec_act[p]);
    const float ro = expf(-dec_out[p]);
    r_act[p] = ra; r_out[p] = ro;
    float ba = 1.f, bo2 = 1.f;
    sqb_act[p] = 1.f;   // t=0: beta=1
    sqb_out[p] = 1.f;
    for (int t = 1; t < T_; t++) {
        ba  = ra * ba  + 1.f;
        bo2 = ro * bo2 + 1.f;
        sqb_act[(size_t)t * REP_ + p] = sqrtf(ba);
        sqb_out[(size_t)t * REP_ + p] = sqrtf(bo2);
    }
}

// ---------------------------------------------------------------------------
__global__ __launch_bounds__(256) void transpose_bf16_kernel(
    const float* __restrict__ in, ushort_t* __restrict__ out, int K, int N)
{
    __shared__ float tile[32][33];
    const int k0 = blockIdx.y * 32, n0 = blockIdx.x * 32;
    const int tx = threadIdx.x & 31, ty4 = (threadIdx.x >> 5) * 4;
    #pragma unroll
    for (int i = 0; i < 4; i++)
        tile[ty4 + i][tx] = in[(size_t)(k0 + ty4 + i) * N + n0 + tx];
    __syncthreads();
    #pragma unroll
    for (int i = 0; i < 4; i++)
        out[(size_t)(n0 + ty4 + i) * K + k0 + tx] = f2bf(tile[tx][ty4 + i]);
}

// ---------------------------------------------------------------------------
__global__ void cast_bf16_kernel(const float* __restrict__ src,
                                 __hip_bfloat16* __restrict__ dst, int n)
{
    const int gid = (blockIdx.x * 256 + threadIdx.x) * 4;
    if (gid >= n) return;
    float4 v = *(const float4*)(src + gid);
    dst[gid + 0] = __float2bfloat16(v.x);
    dst[gid + 1] = __float2bfloat16(v.y);
    dst[gid + 2] = __float2bfloat16(v.z);
    dst[gid + 3] = __float2bfloat16(v.w);
}

// ---------------------------------------------------------------------------
__global__ void feats_kernel(const float* __restrict__ emb,
                             const float* __restrict__ Wp,
                             const float* __restrict__ bp,
                             float* __restrict__ f2)
{
    const int gid = blockIdx.x * 256 + threadIdx.x;
    const int k = gid & 511;
    const int s = (gid >> 9) & (S_ - 1);
    const int c = gid >> 20;
    const float th = 3.14159265358979323846f * (float)s / (float)(S_ - 1);
    f2[gid] = emb[c * 512 + k] + (-sinf(th)) * Wp[k] + cosf(th) * Wp[512 + k] + bp[k];
}

__global__ void init_act_kernel(const float* __restrict__ sa,
                                float* __restrict__ act,
                                float* __restrict__ cat)
{
    const int gid = blockIdx.x * 256 + threadIdx.x;
    const int b = gid >> 11, n = gid & 2047;
    const float v = sa[n];
    act[gid] = v;
    cat[(size_t)b * 2560 + 512 + n] = v;
}

__global__ void init_trace_kernel(const float* __restrict__ st,
                                  float* __restrict__ trace)
{
    const int gid = blockIdx.x * 256 + threadIdx.x;
    trace[gid] = st[gid % (D_MODEL_ * M_)];
}

// ---------------------------------------------------------------------------
// sync (prologue only, t=0 action-sync). y==8 block inits qbuf=bq.
// ---------------------------------------------------------------------------
__global__ void sync_kernel(const float* __restrict__ act,
                            float* __restrict__ alpha,
                            const float* __restrict__ decay,
                            const int t, const int off,
                            ushort_t* __restrict__ sout,
                            float* __restrict__ ib1, const float* __restrict__ bias1, int iN1,
                            float* __restrict__ ib2, const float* __restrict__ bias2, int iN2)
{
    const int b = blockIdx.x;
    const int tid = threadIdx.x;
    if (blockIdx.y == 8) {
        if (ib1)
            for (int n = tid; n < iN1; n += 256)
                ib1[(size_t)b * iN1 + n] = bias1[n];
        if (ib2)
            for (int n = tid; n < iN2; n += 256)
                ib2[(size_t)b * iN2 + n] = bias2[n];
    }
    const int p = blockIdx.y * 256 + tid;
    if (p >= REP_) return;
    int i = 0, rem = p;
    while (rem >= NSY_ - i) { rem -= NSY_ - i; i++; }
    const int j = i + rem;
    const float si = act[(size_t)b * D_MODEL_ + off + i];
    const float sj = act[(size_t)b * D_MODEL_ + off + j];
    const float pair = si * sj;
    const float r = expf(-decay[p]);
    float a;
    if (t == 0) a = pair;
    else        a = r * alpha[(size_t)b * REP_ + p] + pair;
    alpha[(size_t)b * REP_ + p] = a;
    float bta = 1.f;
    for (int k = 0; k < t; k++) bta = r * bta + 1.f;
    sout[(size_t)b * REP_ + p] = f2bf(a / sqrtf(bta));
}

// ---------------------------------------------------------------------------
// fused: state = LN(glu(pre)); contiguous shift-register trace (read tr[1..24]
// vectorizable, write tr[0..24]); Wn proj -> act, cat.
// 512 threads (8 waves) for latency hiding. Epilogues:
//   half==0: sync_out(t) via tables + predt=bout
//   half==1: sync_act(t+1) via tables + qbuf=bq
// ---------------------------------------------------------------------------
__global__ __launch_bounds__(512, 2) void state_trace_kernel(
    const float* __restrict__ pre,    // (B,4096)
    const float* __restrict__ g,
    const float* __restrict__ bt,
    float* __restrict__ trace,        // (B,2048,25)
    const float* __restrict__ ln_g,   // (25)
    const float* __restrict__ ln_b,   // (25)
    const float* __restrict__ Wn,     // (25,2,2048)
    const float* __restrict__ bn,     // (2048,2)
    const float* __restrict__ temp,   // (1)
    float* __restrict__ act,          // (B,2048)
    float* __restrict__ cat,          // (B,2560)
    const int t,
    const int* __restrict__ ijtab,
    const float* __restrict__ r_out,
    const float* __restrict__ sqb_out,
    float* __restrict__ a_o,
    ushort_t* __restrict__ s_outb,
    const float* __restrict__ bout,   // (4096)
    float* __restrict__ predt,        // (B,4096) slab for t
    const float* __restrict__ r_act,
    const float* __restrict__ sqb_act,
    float* __restrict__ a_a,
    ushort_t* __restrict__ s_actb,
    const float* __restrict__ bq,     // (512)
    float* __restrict__ qbuf,         // (B,512)
    const int do_act)
{
    const int b = blockIdx.x >> 1, half = blockIdx.x & 1;
    const int tid = threadIdx.x;          // 0..511
    __shared__ float v[D_MODEL_];
    __shared__ float r1[512], r2[512];
    __shared__ float sh_sync[64];
    float s1 = 0.f, s2 = 0.f;
    #pragma unroll
    for (int i = 0; i < 4; i++) {
        const int dd = tid + i * 512;
        const float g1 = pre[(size_t)b * 4096 + dd];
        const float g2 = pre[(size_t)b * 4096 + 2048 + dd];
        const float val = g1 * (1.f / (1.f + expf(-g2)));
        v[dd] = val; s1 += val; s2 += val * val;
    }
    r1[tid] = s1; r2[tid] = s2; __syncthreads();
    for (int off = 256; off > 0; off >>= 1) {
        if (tid < off) { r1[tid] += r1[tid + off]; r2[tid] += r2[tid + off]; }
        __syncthreads();
    }
    const float mu = r1[0] * (1.f / D_MODEL_);
    const float var = fmaxf(r2[0] * (1.f / D_MODEL_) - mu * mu, 0.f);
    const float sinv = 1.f / sqrtf(var + 1e-5f);
    const float tval = temp[0];

    #pragma unroll
    for (int i = 0; i < 2; i++) {
        const int n = half * 1024 + i * 512 + tid;
        const float sval = (v[n] - mu) * sinv * g[n] + bt[n];
        const int gid = b * 2048 + n;
        float* tr = trace + (size_t)gid * M_;
        float x[M_];
        #pragma unroll
        for (int m = 0; m < M_ - 1; m++) x[m] = tr[m + 1];   // compile-time offsets
        x[M_ - 1] = sval;
        #pragma unroll
        for (int m = 0; m < M_; m++) tr[m] = x[m];
        float t1 = 0.f, t2 = 0.f;
        #pragma unroll
        for (int m = 0; m < M_; m++) { t1 += x[m]; t2 += x[m] * x[m]; }
        const float tmu = t1 * (1.f / M_);
        const float tvar = fmaxf(t2 * (1.f / M_) - tmu * tmu, 0.f);
        const float tinv = 1.f / sqrtf(tvar + 1e-5f);
        float y0 = bn[n * 2 + 0], y1 = bn[n * 2 + 1];
        #pragma unroll
        for (int m = 0; m < M_; m++) {
            const float xn = (x[m] - tmu) * tinv * ln_g[m] + ln_b[m];
            y0 += xn * Wn[(size_t)(m * 2 + 0) * D_MODEL_ + n];
            y1 += xn * Wn[(size_t)(m * 2 + 1) * D_MODEL_ + n];
        }
        const float a = y0 * (1.f / (1.f + expf(-y1))) / tval;
        act[gid] = a;
        cat[(size_t)b * 2560 + 512 + n] = a;
        if (half == 0) {
            if (i == 0 && tid < 64) sh_sync[tid] = a;            // act[b, 0..63]
        } else {
            if (i == 1 && tid >= 448) sh_sync[tid - 448] = a;    // act[b, 1984..2047]
        }
    }
    __syncthreads();

    if (half == 0) {
        // --- fused sync_out(t), off=0, table-driven ---
        for (int p = tid; p < REP_; p += 512) {
            const int ij = ijtab[p];
            const float pair = sh_sync[ij >> 16] * sh_sync[ij & 0xffff];
            const float r = r_out[p];
            float a2;
            if (t == 0) a2 = pair;
            else        a2 = r * a_o[(size_t)b * REP_ + p] + pair;
            a_o[(size_t)b * REP_ + p] = a2;
            s_outb[(size_t)b * REP_ + p] = f2bf(a2 / sqb_out[(size_t)t * REP_ + p]);
        }
        // predt = bout (arm split-K atomic target for Wout-GEMM(t))
        const float4* b4 = (const float4*)bout;
        float4* pd = (float4*)(predt + (size_t)b * 4096);
        for (int idx = tid; idx < 1024; idx += 512) pd[idx] = b4[idx];
    } else if (do_act) {
        // --- fused sync_act(t+1), off=1984, table-driven ---
        for (int p = tid; p < REP_; p += 512) {
            const int ij = ijtab[p];
            const float pair = sh_sync[ij >> 16] * sh_sync[ij & 0xffff];
            const float r = r_act[p];
            float a2 = r * a_a[(size_t)b * REP_ + p] + pair;    // t+1 >= 1
            a_a[(size_t)b * REP_ + p] = a2;
            s_actb[(size_t)b * REP_ + p] = f2bf(a2 / sqb_act[(size_t)(t + 1) * REP_ + p]);
        }
        // qbuf = bq (arm split-K atomic target for q-GEMM(t+1))
        const float4* b4 = (const float4*)bq;
        float4* qb = (float4*)(qbuf + (size_t)b * 512);
        if (tid < 128) qb[tid] = b4[tid];
    }
}

// ---------------------------------------------------------------------------
// Batched entropy over ALL T slabs — once after the loop. grid = T*B blocks.
// ---------------------------------------------------------------------------
__global__ __launch_bounds__(256) void ent_all_kernel(
    const float* __restrict__ predst,  // (T, B*4096)
    float* __restrict__ certbf)        // (T, B*2)
{
    const int t = blockIdx.x >> 7;
    const int b = blockIdx.x & 127;
    const int tid = threadIdx.x;
    __shared__ float red[256];
    const float* pr = predst + (size_t)t * PRED_N + (size_t)b * 4096;
    float sum = 0.f;
    #pragma unroll
    for (int i = 0; i < 8; i++) {
        const int s = tid + i * 256;
        const float l0 = pr[2 * s], l1 = pr[2 * s + 1];
        const float mm = fmaxf(l0, l1);
        const float z0 = expf(l0 - mm), z1 = expf(l1 - mm);
        const float Z = z0 + z1;
        const float lz = logf(Z);
        const float p0 = z0 / Z, p1 = z1 / Z;
        const float lp0 = (l0 - mm) - lz, lp1 = (l1 - mm) - lz;
        sum += -(p0 * lp0 + p1 * lp1) * 1.4426950408889634f;
    }
    red[tid] = sum; __syncthreads();
    for (int off = 128; off > 0; off >>= 1) {
        if (tid < off) red[tid] += red[tid + off];
        __syncthreads();
    }
    if (tid == 0) {
        const float ne = red[0] * (1.f / S_);
        certbf[(size_t)t * B_ * 2 + b * 2 + 0] = ne;
        certbf[(size_t)t * B_ * 2 + b * 2 + 1] = 1.f - ne;
    }
}

// ---------------------------------------------------------------------------
__global__ __launch_bounds__(256) void finalize_kernel(
    const float* __restrict__ predstage,  // (T, B*4096)
    const float* __restrict__ certbuf,    // (T, B*2)
    float* __restrict__ dout)
{
    __shared__ float tile[T_][1024];
    const int tid = threadIdx.x;
    const int row0 = blockIdx.x * 1024;
    #pragma unroll
    for (int t = 0; t < T_; t++) {
        float4 v = *(const float4*)(predstage + (size_t)t * PRED_N + row0 + tid * 4);
        tile[t][tid * 4 + 0] = v.x; tile[t][tid * 4 + 1] = v.y;
        tile[t][tid * 4 + 2] = v.z; tile[t][tid * 4 + 3] = v.w;
    }
    __syncthreads();
    float buf[40];
    #pragma unroll
    for (int r = 0; r < 4; r++)
        #pragma unroll
        for (int t = 0; t < T_; t++)
            buf[r * 10 + t] = tile[t][tid * 4 + r];
    float* dst = dout + (size_t)(row0 + tid * 4) * T_;
    #pragma unroll
    for (int k = 0; k < 10; k++)
        *(float4*)(dst + k * 4) = make_float4(buf[4*k], buf[4*k+1], buf[4*k+2], buf[4*k+3]);

    if (blockIdx.x == 0 && tid < B_) {
        const int b = tid;
        const size_t base = (size_t)PRED_N * T_;
        #pragma unroll
        for (int t = 0; t < T_; t++) {
            dout[base + (size_t)(b * 2 + 0) * T_ + t] = certbuf[t * B_ * 2 + b * 2 + 0];
            dout[base + (size_t)(b * 2 + 1) * T_ + t] = certbuf[t * B_ * 2 + b * 2 + 1];
        }
    }
}

// ---------------------------------------------------------------------------
extern "C" void kernel_launch(void* const* d_in, const int* in_sizes, int n_in,
                              void* d_out, int out_size, void* d_ws, size_t ws_size,
                              hipStream_t stream)
{
    const int*   tokens    = (const int*)  d_in[0];
    const float* emb       = (const float*)d_in[1];
    const float* W_pos     = (const float*)d_in[2];
    const float* b_pos     = (const float*)d_in[3];
    const float* Wq        = (const float*)d_in[4];
    const float* bq        = (const float*)d_in[5];
    const float* Wk        = (const float*)d_in[6];
    const float* bk        = (const float*)d_in[7];
    const float* Wv        = (const float*)d_in[8];
    const float* bv        = (const float*)d_in[9];
    const float* Wo        = (const float*)d_in[10];
    const float* bo        = (const float*)d_in[11];
    const float* Ws        = (const float*)d_in[12];
    const float* bs        = (const float*)d_in[13];
    const float* ln_s_g    = (const float*)d_in[14];
    const float* ln_s_b    = (const float*)d_in[15];
    const float* ln_n_g    = (const float*)d_in[16];
    const float* ln_n_b    = (const float*)d_in[17];
    const float* Wn        = (const float*)d_in[18];
    const float* bn        = (const float*)d_in[19];
    const float* temp      = (const float*)d_in[20];
    const float* Wout      = (const float*)d_in[21];
    const float* bout      = (const float*)d_in[22];
    const float* start_act = (const float*)d_in[23];
    const float* start_tr  = (const float*)d_in[24];
    const float* dec_act   = (const float*)d_in[25];
    const float* dec_out   = (const float*)d_in[26];
    float* out = (float*)d_out;
    float* w = (float*)d_ws;

    // workspace layout (floats)
    size_t off = 0;
    float* f2     = w + off; off += (size_t)2 * S_ * 512;
    float* Ktab   = w + off; off += (size_t)2 * S_ * 512;
    float* Vtab   = w + off; off += (size_t)2 * S_ * 512;
    float* act    = w + off; off += (size_t)B_ * D_MODEL_;
    float* cat    = w + off; off += (size_t)B_ * 2560;
    float* a_a    = w + off; off += (size_t)B_ * REP_;
    float* a_o    = w + off; off += (size_t)B_ * REP_;
    float* qbuf   = w + off; off += (size_t)B_ * 512;
    float* o_attn = w + off; off += (size_t)B_ * 512;
    float* pre    = w + off; off += (size_t)B_ * 4096;
    float* trace  = w + off; off += (size_t)B_ * D_MODEL_ * M_;
    float* scbuf  = w + off; off += (size_t)16 * 128 * S_;
    float* predst = w + off; off += (size_t)T_ * PRED_N;     // (T, B*4096)
    float* certbf = w + off; off += (size_t)T_ * B_ * 2;
    ushort_t* s_actb = (ushort_t*)(w + off); off += (size_t)B_ * REP_ / 2;
    ushort_t* s_outb = (ushort_t*)(w + off); off += (size_t)B_ * REP_ / 2;
    __hip_bfloat16* Kb = (__hip_bfloat16*)(w + off); off += (size_t)S_ * 512;
    ushort_t* Pbuf  = (ushort_t*)(w + off); off += (size_t)8 * 128 * 4096 / 2;
    ushort_t* VT    = (ushort_t*)(w + off); off += (size_t)8 * 64 * 4096 / 2;
    ushort_t* WkT   = (ushort_t*)(w + off); off += (size_t)512 * 512 / 2;
    ushort_t* WvT   = (ushort_t*)(w + off); off += (size_t)512 * 512 / 2;
    ushort_t* WqT   = (ushort_t*)(w + off); off += (size_t)512 * REP_ / 2;
    ushort_t* WoT   = (ushort_t*)(w + off); off += (size_t)512 * 512 / 2;
    ushort_t* WsT   = (ushort_t*)(w + off); off += (size_t)4096 * 2560 / 2;
    ushort_t* WoutT = (ushort_t*)(w + off); off += (size_t)4096 * REP_ / 2;
    int*   ijtab = (int*)(w + off); off += REP_;
    float* r_actT = w + off; off += REP_;
    float* r_outT = w + off; off += REP_;
    float* sqb_a  = w + off; off += (size_t)T_ * REP_;
    float* sqb_o  = w + off; off += (size_t)T_ * REP_;

    // ---- pre-loop ----
    feats_kernel<<<(2 * S_ * 512) / 256, 256, 0, stream>>>(emb, W_pos, b_pos, f2);
    init_act_kernel<<<(B_ * D_MODEL_) / 256, 256, 0, stream>>>(start_act, act, cat);
    init_trace_kernel<<<(B_ * D_MODEL_ * M_) / 256, 256, 0, stream>>>(start_tr, trace);
    build_sync_tabs<<<(REP_ + 255) / 256, 256, 0, stream>>>(
        dec_act, dec_out, ijtab, r_actT, r_outT, sqb_a, sqb_o);

    transpose_bf16_kernel<<<dim3(512 / 32, 512 / 32), 256, 0, stream>>>(Wk, WkT, 512, 512);
    transpose_bf16_kernel<<<dim3(512 / 32, 512 / 32), 256, 0, stream>>>(Wv, WvT, 512, 512);
    transpose_bf16_kernel<<<dim3(512 / 32, REP_ / 32), 256, 0, stream>>>(Wq, WqT, REP_, 512);
    transpose_bf16_kernel<<<dim3(512 / 32, 512 / 32), 256, 0, stream>>>(Wo, WoT, 512, 512);
    transpose_bf16_kernel<<<dim3(4096 / 32, 2560 / 32), 256, 0, stream>>>(Ws, WsT, 2560, 4096);
    transpose_bf16_kernel<<<dim3(4096 / 32, REP_ / 32), 256, 0, stream>>>(Wout, WoutT, REP_, 4096);

    gemm_bf16<<<dim3(512 / 128, (2 * S_) / 64, 1), 256, 0, stream>>>(
        f2, 512, WkT, 512, bk, Ktab, 512, 2 * S_, 512, 512, 512);
    gemm_bf16<<<dim3(512 / 128, (2 * S_) / 64, 1), 256, 0, stream>>>(
        f2, 512, WvT, 512, bv, Vtab, 512, 2 * S_, 512, 512, 512);
    cast_bf16_kernel<<<(2 * S_ * 512 / 4) / 256, 256, 0, stream>>>(Ktab, Kb, 2 * S_ * 512);
    build_vt<<<(8 * 64 * 4096) / 256, 256, 0, stream>>>(Vtab, VT);

    // t=0 action-sync (from init act); y==8 block inits qbuf=bq
    sync_kernel<<<dim3(B_, 9), 256, 0, stream>>>(
        act, a_a, dec_act, 0, D_MODEL_ - NSY_, s_actb,
        qbuf, bq, 512, nullptr, nullptr, 0);
    // q-GEMM(0)
    gemm_bb<<<dim3(512 / 128, 2, 13), 256, 0, stream>>>(
        s_actb, REP_, WqT, REP_, bq, qbuf, 512, B_, 512, REP_, 160);

    // ---- T iterations (7 launches each) ----
    for (int t = 0; t < T_; t++) {
        gemm_qk<<<dim3(S_ / 128, 2, 16), 256, 0, stream>>>(
            qbuf, (const ushort_t*)Kb, scbuf);
        // attn_soft also re-arms pre=bs (blocks 320..831) for Ws-GEMM(t)
        attn_soft<<<B_ * H_, 256, 0, stream>>>(
            scbuf, tokens, Pbuf, o_attn, cat, bo, bs, pre);
        gemm_pv<<<dim3(2, 8, 8), 256, 0, stream>>>(Pbuf, VT, o_attn);

        gemm_bf16<<<dim3(512 / 128, 2, 8), 256, 0, stream>>>(
            o_attn, 512, WoT, 512, bo, cat, 2560, B_, 512, 512, 64);

        gemm_bf16<<<dim3(4096 / 128, 2, 8), 256, 0, stream>>>(
            cat, 2560, WsT, 2560, bs, pre, 4096, B_, 4096, 2560, 320);

        float* predt = predst + (size_t)t * PRED_N;
        // fused: state/trace/act + sync_out(t) + predt=bout + sync_act(t+1) + qbuf=bq
        state_trace_kernel<<<B_ * 2, 512, 0, stream>>>(
            pre, ln_s_g, ln_s_b, trace, ln_n_g, ln_n_b, Wn, bn, temp, act, cat,
            t, ijtab,
            r_outT, sqb_o, a_o, s_outb, bout, predt,
            r_actT, sqb_a, a_a, s_actb, bq, qbuf, (t < T_ - 1) ? 1 : 0);

        // merged: Wout-GEMM(t) [320 blocks] + q-GEMM(t+1) [104 blocks, skip at t=9]
        const int blocks2 = (t < T_ - 1) ? 104 : 0;
        gemm_bb_dual<<<dim3(320 + blocks2), 256, 0, stream>>>(
            s_outb, REP_, WoutT, REP_, predt, 4096, 416, 32, 320,
            s_actb, REP_, WqT, REP_, qbuf, 512, 160, 4);
    }

    // batched entropy (all t at once), then the coalesced output pass
    ent_all_kernel<<<T_ * B_, 256, 0, stream>>>(predst, certbf);
    finalize_kernel<<<PRED_N / 1024, 256, 0, stream>>>(predst, certbf, out);
}